// Round 9
// baseline (392.592 us; speedup 1.0000x reference)
//
#include <hip/hip_runtime.h>
#include <hip/hip_bf16.h>

// GCNConv, gather formulation. History:
//  R1: scatter f32 atomics (400MB EA write-through)        566us
//  R3: CSR gather (random-atomic fill)                     500us
//  R5: bf16 h + MFMA gemm                                  398us
//  R6: bucket counting-sort CSR, register-accum gather     247us
//  R7: LDS-f32-atomic fused gather — REGRESSION            750us (ds_add serial)
//  R8: packed u32 edges, CSR build fused into gather       215us (gather 70us,
//      latency-bound: ~1 outstanding load/wave, 24 waves/CU)
//  R9: fixed-cap buckets + global-atomic claim (deletes hist+2 scans);
//      gather 16-lane edge groups + x2 unroll (4x MLP); wt fused into gemm.
constexpr int N_NODES = 100000;
constexpr int IN_F    = 128;
constexpr int OUT_F   = 64;
constexpr int N_EDGES = 1600000;

constexpr int NPB = 64;                        // nodes per bucket (col>>6)
constexpr int NB  = (N_NODES + NPB - 1) / NPB; // 1563 buckets
constexpr int CAP = 2048;                      // bucket capacity (mean 1024, +32 sigma)

typedef short bf16x8 __attribute__((ext_vector_type(8)));
typedef float f32x4  __attribute__((ext_vector_type(4)));

static __device__ __forceinline__ unsigned short f2b(float f) {
    __hip_bfloat16 h = __float2bfloat16(f);
    return *reinterpret_cast<unsigned short*>(&h);
}
static __device__ __forceinline__ float blo(unsigned int u) {
    return __uint_as_float(u << 16);
}
static __device__ __forceinline__ float bhi(unsigned int u) {
    return __uint_as_float(u & 0xffff0000u);
}

// ---- K1: bucket-partition packed edges, global-atomic slot claim ----------
__global__ __launch_bounds__(256) void scatter_kernel(const int* __restrict__ eidx,
                                                      int* __restrict__ gcount,
                                                      unsigned int* __restrict__ packs) {
    int i = blockIdx.x * blockDim.x + threadIdx.x;
    int stride = gridDim.x * blockDim.x;
    for (int e = i; e < N_EDGES; e += stride) {
        int row = eidx[e];
        int col = eidx[N_EDGES + e];
        int b   = col >> 6;
        int slot = atomicAdd(&gcount[b], 1);
        if (slot < CAP)                       // statistically impossible to fail
            packs[b * CAP + slot] = ((unsigned)row << 6) | (unsigned)(col & 63);
    }
}

// ---- K2: per-bucket degree -> dis = rsqrt(deg+1) --------------------------
__global__ __launch_bounds__(256) void degdis_kernel(const unsigned int* __restrict__ packs,
                                                     const int* __restrict__ gcount,
                                                     float* __restrict__ dis) {
    __shared__ int cnt[NPB];
    const int b = blockIdx.x, t = threadIdx.x;
    if (t < NPB) cnt[t] = 0;
    __syncthreads();
    const int size = min(gcount[b], CAP);
    const int base = b * CAP;
    for (int i = t; i < size; i += 256)
        atomicAdd(&cnt[packs[base + i] & 63], 1);
    __syncthreads();
    const int n0 = b << 6;
    if (t < NPB && n0 + t < N_NODES)
        dis[n0 + t] = rsqrtf((float)cnt[t] + 1.0f);
}

// ---- K3: hb = bf16(dis * (x @ W)) -----------------------------------------
// mfma_f32_16x16x32_bf16; LDS XOR-swizzled bf16 tiles (verified R5-R8).
// W staged f32->bf16 transposed in-kernel (wt_kernel fused away).
constexpr int GEMM_ROWS = 64;
__global__ __launch_bounds__(256) void gemm_kernel(const float* __restrict__ x,
                                                   const float* __restrict__ W,
                                                   const float* __restrict__ dis,
                                                   unsigned short* __restrict__ h) {
    __shared__ unsigned short Xs[GEMM_ROWS][IN_F];   // 16 KB
    __shared__ unsigned short Ws[OUT_F][IN_F];       // 16 KB (W^T: [n][k])
    const int tid = threadIdx.x;
    const int row0 = blockIdx.x * GEMM_ROWS;

    // stage W^T: lane n reads k..k+3 at stride 64 (L2-resident), packs 4 bf16
    {
        int n  = tid & 63;
        int sw = (n & 7) << 3;
        for (int kg = tid >> 6; kg < IN_F / 4; kg += 4) {
            int k = kg * 4;
            float w0 = W[(k + 0) * 64 + n];
            float w1 = W[(k + 1) * 64 + n];
            float w2 = W[(k + 2) * 64 + n];
            float w3 = W[(k + 3) * 64 + n];
            unsigned int u0 = (unsigned int)f2b(w0) | ((unsigned int)f2b(w1) << 16);
            unsigned int u1 = (unsigned int)f2b(w2) | ((unsigned int)f2b(w3) << 16);
            uint2 pr; pr.x = u0; pr.y = u1;
            *(uint2*)&Ws[n][k ^ sw] = pr;
        }
    }
    // stage X rows (f32 global -> bf16 LDS, swizzled), 4 threads/row
    {
        int r    = tid >> 2;
        int grow = row0 + r;
        if (grow >= N_NODES) grow = N_NODES - 1;
        int ks   = (tid & 3) * 32;
        const float4* xp = (const float4*)x + (long)grow * (IN_F / 4) + (ks >> 2);
        int sw = (r & 7) << 3;
#pragma unroll
        for (int j = 0; j < 8; ++j) {
            float4 xv = xp[j];
            unsigned int u0 = (unsigned int)f2b(xv.x) | ((unsigned int)f2b(xv.y) << 16);
            unsigned int u1 = (unsigned int)f2b(xv.z) | ((unsigned int)f2b(xv.w) << 16);
            uint2 pr; pr.x = u0; pr.y = u1;
            *(uint2*)&Xs[r][(ks + j * 4) ^ sw] = pr;
        }
    }
    __syncthreads();

    const int w    = tid >> 6;
    const int lane = tid & 63;
    const int ml   = lane & 15;
    const int kg   = lane >> 4;

    const int rowA = w * 16 + ml;
    const int swA  = (rowA & 7) << 3;

    bf16x8 a[4];
#pragma unroll
    for (int kt = 0; kt < 4; ++kt)
        a[kt] = *(const bf16x8*)&Xs[rowA][(kt * 32 + kg * 8) ^ swA];

    f32x4 acc[4];
#pragma unroll
    for (int ct = 0; ct < 4; ++ct) acc[ct] = (f32x4)(0.0f);

#pragma unroll
    for (int ct = 0; ct < 4; ++ct) {
        int n  = ct * 16 + ml;
        int sw = (n & 7) << 3;
#pragma unroll
        for (int kt = 0; kt < 4; ++kt) {
            bf16x8 bv = *(const bf16x8*)&Ws[n][(kt * 32 + kg * 8) ^ sw];
            acc[ct] = __builtin_amdgcn_mfma_f32_16x16x32_bf16(a[kt], bv, acc[ct], 0, 0, 0);
        }
    }

    const int grow0 = row0 + w * 16 + kg * 4;
#pragma unroll
    for (int i = 0; i < 4; ++i) {
        int r = grow0 + i;
        if (r < N_NODES) {
            float ds = dis[r];
#pragma unroll
            for (int ct = 0; ct < 4; ++ct)
                h[(long)r * OUT_F + ct * 16 + ml] = f2b(ds * acc[ct][i]);
        }
    }
}

// ---- K4: fused CSR-build + gather (register accum, 16-lane edge groups) ---
// One block per bucket: stage packs in LDS, per-node count/scan/reorder in
// LDS (int atomics, wave-shuffle scan), then 4 waves x 16 nodes each.
// Quarter-wave q handles every 4th edge; lane ql = features 4ql..4ql+3 as
// uint2 (8B). x2 unroll -> 2 outstanding 512B loads/wave (4x MLP vs R8).
// out = dc*(sum hb[row] + hb[node]) + b   (hb pre-scaled by dis).
__global__ __launch_bounds__(256) void gather_kernel(const unsigned int* __restrict__ packs,
                                                     const int* __restrict__ gcount,
                                                     const float* __restrict__ dis,
                                                     const uint2* __restrict__ h4,
                                                     const float* __restrict__ bias,
                                                     float* __restrict__ out) {
    __shared__ unsigned int stage[CAP];
    __shared__ unsigned int sorted[CAP];
    __shared__ int cnt[NPB], sx[NPB], curs[NPB];
    __shared__ float disL[NPB];
    const int b = blockIdx.x, t = threadIdx.x;
    const int size = min(gcount[b], CAP);
    const int base = b * CAP;
    const int n0 = b << 6;

    if (t < NPB) {
        cnt[t] = 0;
        disL[t] = (n0 + t < N_NODES) ? dis[n0 + t] : 0.0f;
    }
    __syncthreads();
    for (int i = t; i < size; i += 256) {
        unsigned int pk = packs[base + i];
        stage[i] = pk;
        atomicAdd(&cnt[pk & 63], 1);
    }
    __syncthreads();
    if (t < NPB) {                       // wave-0 shuffle scan over 64 bins
        int v = cnt[t];
        int s = v;
#pragma unroll
        for (int off = 1; off < NPB; off <<= 1) {
            int u = __shfl_up(s, off);
            if (t >= off) s += u;
        }
        sx[t] = s;                        // inclusive
        curs[t] = s - v;                  // exclusive
    }
    __syncthreads();
    for (int i = t; i < size; i += 256) {
        unsigned int pk = stage[i];
        int q = atomicAdd(&curs[pk & 63], 1);
        sorted[q] = pk;
    }
    __syncthreads();

    const int lane = t & 63;
    const int q    = lane >> 4;          // quarter 0..3
    const int ql   = lane & 15;          // feature group (4 features)
    const int w    = t >> 6;

    for (int c = w; c < NPB; c += 4) {
        int node = n0 + c;
        if (node >= N_NODES) break;      // uniform per wave
        int s1 = sx[c], s0 = s1 - cnt[c];
        float a0 = 0.f, a1 = 0.f, a2 = 0.f, a3 = 0.f;
        int i = s0 + q;
        for (; i + 4 < s1; i += 8) {     // 2 independent loads in flight
            unsigned int pk0 = sorted[i];
            unsigned int pk1 = sorted[i + 4];
            uint2 u0 = h4[(pk0 >> 6) * 16 + ql];
            uint2 u1 = h4[(pk1 >> 6) * 16 + ql];
            a0 += blo(u0.x); a1 += bhi(u0.x); a2 += blo(u0.y); a3 += bhi(u0.y);
            a0 += blo(u1.x); a1 += bhi(u1.x); a2 += blo(u1.y); a3 += bhi(u1.y);
        }
        if (i < s1) {
            unsigned int pk = sorted[i];
            uint2 u = h4[(pk >> 6) * 16 + ql];
            a0 += blo(u.x); a1 += bhi(u.x); a2 += blo(u.y); a3 += bhi(u.y);
        }
        a0 += __shfl_xor(a0, 16); a0 += __shfl_xor(a0, 32);
        a1 += __shfl_xor(a1, 16); a1 += __shfl_xor(a1, 32);
        a2 += __shfl_xor(a2, 16); a2 += __shfl_xor(a2, 32);
        a3 += __shfl_xor(a3, 16); a3 += __shfl_xor(a3, 32);

        if (q == 0) {
            float dc = disL[c];
            uint2 us = h4[node * 16 + ql];          // hb[node] = dis*h
            float4 bv = ((const float4*)bias)[ql];
            float4 o;
            o.x = dc * (a0 + blo(us.x)) + bv.x;
            o.y = dc * (a1 + bhi(us.x)) + bv.y;
            o.z = dc * (a2 + blo(us.y)) + bv.z;
            o.w = dc * (a3 + bhi(us.y)) + bv.w;
            ((float4*)out)[node * 16 + ql] = o;
        }
    }
}

// ---------------------------------------------------------------------------
extern "C" void kernel_launch(void* const* d_in, const int* in_sizes, int n_in,
                              void* d_out, int out_size, void* d_ws, size_t ws_size,
                              hipStream_t stream) {
    const float* x   = (const float*)d_in[0];
    const int*   idx = (const int*)d_in[1];   // [2, E], delivered as int32
    const float* W   = (const float*)d_in[2];
    const float* b   = (const float*)d_in[3];
    float*       out = (float*)d_out;

    int* p = (int*)d_ws;
    unsigned int* packs = (unsigned int*)p;  p += NB * CAP;      // 12.8 MB
    int* gcount   = p;                       p += NB + 4;
    float* dis    = (float*)p;               p += N_NODES;
    p = (int*)(((uintptr_t)p + 15) & ~(uintptr_t)15);            // 16B align
    unsigned short* hb = (unsigned short*)p;                     // 12.8 MB

    hipMemsetAsync(gcount, 0, (NB + 4) * sizeof(int), stream);
    scatter_kernel<<<1024, 256, 0, stream>>>(idx, gcount, packs);
    degdis_kernel<<<NB, 256, 0, stream>>>(packs, gcount, dis);
    gemm_kernel<<<(N_NODES + GEMM_ROWS - 1) / GEMM_ROWS, 256, 0, stream>>>(x, W, dis, hb);
    gather_kernel<<<NB, 256, 0, stream>>>(packs, gcount, dis,
                                          (const uint2*)hb, b, out);
}

// Round 11
// 200.151 us; speedup vs baseline: 1.9615x; 1.9615x over previous
//
#include <hip/hip_runtime.h>
#include <hip/hip_bf16.h>

// GCNConv, gather formulation. History:
//  R1: scatter f32 atomics (400MB EA write-through)        566us
//  R3: CSR gather (random-atomic fill)                     500us
//  R5: bf16 h + MFMA gemm                                  398us
//  R6: bucket counting-sort CSR, register-accum gather     247us
//  R7: LDS-f32-atomic fused gather — REGRESSION            750us (ds_add serial)
//  R8: packed edges, CSR build fused into gather           215us (gather 70us)
//  R9: global-atomic bucket claim — REGRESSION             392us (scatter 239us:
//      cross-XCD bucket-tail line ping-pong, 76MB write amplification)
//  R10: deterministic sort restored, coarse 256-node sort buckets (private
//       64B write runs); gather filters coarse bucket; R9 gather/gemm kept.
constexpr int N_NODES = 100000;
constexpr int IN_F    = 128;
constexpr int OUT_F   = 64;
constexpr int N_EDGES = 1600000;

constexpr int NPB_S  = 256;                          // sort bucket nodes (col>>8)
constexpr int NB_S   = (N_NODES + NPB_S - 1) / NPB_S;  // 391
constexpr int NPB_G  = 64;                           // gather group nodes
constexpr int NB_G   = (N_NODES + NPB_G - 1) / NPB_G;  // 1563
constexpr int B_SORT = 256;                          // hist/scatter blocks
constexpr int EPB    = N_EDGES / B_SORT;             // 6250 (exact)
constexpr int CAP    = 1600;                         // 64-group stage cap (mean 1024)

typedef short bf16x8 __attribute__((ext_vector_type(8)));
typedef float f32x4  __attribute__((ext_vector_type(4)));

static __device__ __forceinline__ unsigned short f2b(float f) {
    __hip_bfloat16 h = __float2bfloat16(f);
    return *reinterpret_cast<unsigned short*>(&h);
}
static __device__ __forceinline__ float blo(unsigned int u) {
    return __uint_as_float(u << 16);
}
static __device__ __forceinline__ float bhi(unsigned int u) {
    return __uint_as_float(u & 0xffff0000u);
}

// --------------------------------------------- K1: per-block bucket histogram
__global__ __launch_bounds__(256) void hist_kernel(const int* __restrict__ col,
                                                   int* __restrict__ hist_g) {
    __shared__ int hist[NB_S];
    for (int i = threadIdx.x; i < NB_S; i += 256) hist[i] = 0;
    __syncthreads();
    const int beg = blockIdx.x * EPB;
    for (int e = beg + threadIdx.x; e < beg + EPB; e += 256)
        atomicAdd(&hist[col[e] >> 8], 1);
    __syncthreads();
    for (int i = threadIdx.x; i < NB_S; i += 256)
        hist_g[i * B_SORT + blockIdx.x] = hist[i];
}

// ------------------- K2a: per-bucket scan over blocks (in-place) + bin totals
__global__ __launch_bounds__(B_SORT) void scanbins_kernel(int* __restrict__ hist_g,
                                                          int* __restrict__ binTotal) {
    __shared__ int s[B_SORT];
    const int bin = blockIdx.x, t = threadIdx.x;
    int v = hist_g[bin * B_SORT + t];
    s[t] = v;
    __syncthreads();
#pragma unroll
    for (int off = 1; off < B_SORT; off <<= 1) {
        int u = (t >= off) ? s[t - off] : 0;
        __syncthreads();
        s[t] += u;
        __syncthreads();
    }
    hist_g[bin * B_SORT + t] = s[t] - v;          // exclusive within bin
    if (t == B_SORT - 1) binTotal[bin] = s[t];
}

// --------------------- K2b: scan bucket totals -> bucket starts -------------
__global__ __launch_bounds__(512) void scanoff_kernel(const int* __restrict__ binTotal,
                                                      int* __restrict__ binStart) {
    __shared__ int s[512];
    const int t = threadIdx.x;
    int v = (t < NB_S) ? binTotal[t] : 0;
    s[t] = v;
    __syncthreads();
#pragma unroll
    for (int off = 1; off < 512; off <<= 1) {
        int u = (t >= off) ? s[t - off] : 0;
        __syncthreads();
        s[t] += u;
        __syncthreads();
    }
    if (t < NB_S) binStart[t] = s[t] - v;
    if (t == 0) binStart[NB_S] = N_EDGES;
}

// ---- K3: bucket-partition packed edges (LDS cursors, deterministic runs) --
__global__ __launch_bounds__(256) void scatter_kernel(const int* __restrict__ eidx,
                                                      const int* __restrict__ hist_g,
                                                      const int* __restrict__ binStart,
                                                      unsigned int* __restrict__ packs) {
    __shared__ int cur[NB_S];
    for (int i = threadIdx.x; i < NB_S; i += 256)
        cur[i] = binStart[i] + hist_g[i * B_SORT + blockIdx.x];
    __syncthreads();
    const int beg = blockIdx.x * EPB;
    for (int e = beg + threadIdx.x; e < beg + EPB; e += 256) {
        int row = eidx[e];
        int col = eidx[N_EDGES + e];
        int p = atomicAdd(&cur[col >> 8], 1);     // LDS atomic only
        packs[p] = ((unsigned)row << 8) | (unsigned)(col & 255);
    }
}

// ---- K4: per-coarse-bucket degree -> dis = rsqrt(deg+1) -------------------
__global__ __launch_bounds__(256) void degdis_kernel(const unsigned int* __restrict__ packs,
                                                     const int* __restrict__ binStart,
                                                     float* __restrict__ dis) {
    __shared__ int cnt[NPB_S];
    const int B = blockIdx.x, t = threadIdx.x;
    cnt[t] = 0;
    __syncthreads();
    const int beg = binStart[B], end = binStart[B + 1];
    for (int i = beg + t; i < end; i += 256)
        atomicAdd(&cnt[packs[i] & 255], 1);
    __syncthreads();
    const int node = (B << 8) + t;
    if (node < N_NODES) dis[node] = rsqrtf((float)cnt[t] + 1.0f);
}

// ---- K5: hb = bf16(dis * (x @ W)) -----------------------------------------
// mfma_f32_16x16x32_bf16; LDS XOR-swizzled bf16 tiles (verified R5-R9).
constexpr int GEMM_ROWS = 64;
__global__ __launch_bounds__(256) void gemm_kernel(const float* __restrict__ x,
                                                   const float* __restrict__ W,
                                                   const float* __restrict__ dis,
                                                   unsigned short* __restrict__ h) {
    __shared__ unsigned short Xs[GEMM_ROWS][IN_F];   // 16 KB
    __shared__ unsigned short Ws[OUT_F][IN_F];       // 16 KB (W^T: [n][k])
    const int tid = threadIdx.x;
    const int row0 = blockIdx.x * GEMM_ROWS;

    {   // stage W^T f32->bf16 (L2-resident), swizzled
        int n  = tid & 63;
        int sw = (n & 7) << 3;
        for (int kg = tid >> 6; kg < IN_F / 4; kg += 4) {
            int k = kg * 4;
            float w0 = W[(k + 0) * 64 + n];
            float w1 = W[(k + 1) * 64 + n];
            float w2 = W[(k + 2) * 64 + n];
            float w3 = W[(k + 3) * 64 + n];
            unsigned int u0 = (unsigned int)f2b(w0) | ((unsigned int)f2b(w1) << 16);
            unsigned int u1 = (unsigned int)f2b(w2) | ((unsigned int)f2b(w3) << 16);
            uint2 pr; pr.x = u0; pr.y = u1;
            *(uint2*)&Ws[n][k ^ sw] = pr;
        }
    }
    {   // stage X rows f32->bf16, swizzled, 4 threads/row
        int r    = tid >> 2;
        int grow = row0 + r;
        if (grow >= N_NODES) grow = N_NODES - 1;
        int ks   = (tid & 3) * 32;
        const float4* xp = (const float4*)x + (long)grow * (IN_F / 4) + (ks >> 2);
        int sw = (r & 7) << 3;
#pragma unroll
        for (int j = 0; j < 8; ++j) {
            float4 xv = xp[j];
            unsigned int u0 = (unsigned int)f2b(xv.x) | ((unsigned int)f2b(xv.y) << 16);
            unsigned int u1 = (unsigned int)f2b(xv.z) | ((unsigned int)f2b(xv.w) << 16);
            uint2 pr; pr.x = u0; pr.y = u1;
            *(uint2*)&Xs[r][(ks + j * 4) ^ sw] = pr;
        }
    }
    __syncthreads();

    const int w    = tid >> 6;
    const int lane = tid & 63;
    const int ml   = lane & 15;
    const int kg   = lane >> 4;

    const int rowA = w * 16 + ml;
    const int swA  = (rowA & 7) << 3;

    bf16x8 a[4];
#pragma unroll
    for (int kt = 0; kt < 4; ++kt)
        a[kt] = *(const bf16x8*)&Xs[rowA][(kt * 32 + kg * 8) ^ swA];

    f32x4 acc[4];
#pragma unroll
    for (int ct = 0; ct < 4; ++ct) acc[ct] = (f32x4)(0.0f);

#pragma unroll
    for (int ct = 0; ct < 4; ++ct) {
        int n  = ct * 16 + ml;
        int sw = (n & 7) << 3;
#pragma unroll
        for (int kt = 0; kt < 4; ++kt) {
            bf16x8 bv = *(const bf16x8*)&Ws[n][(kt * 32 + kg * 8) ^ sw];
            acc[ct] = __builtin_amdgcn_mfma_f32_16x16x32_bf16(a[kt], bv, acc[ct], 0, 0, 0);
        }
    }

    const int grow0 = row0 + w * 16 + kg * 4;
#pragma unroll
    for (int i = 0; i < 4; ++i) {
        int r = grow0 + i;
        if (r < N_NODES) {
            float ds = dis[r];
#pragma unroll
            for (int ct = 0; ct < 4; ++ct)
                h[(long)r * OUT_F + ct * 16 + ml] = f2b(ds * acc[ct][i]);
        }
    }
}

// ---- K6: fused CSR-build + gather (register accum, quarter-wave groups) ---
// Block b: stream coarse bucket b>>2, filter subgroup b&3, count/scan/place
// into LDS sorted (int atomics). Then 4 waves x 16 nodes: quarter-wave q
// takes every 4th edge, lane ql = features 4ql..4ql+3 (uint2), x2 unroll ->
// 2 loads in flight. out = dc*(sum hb[row] + hb[node]) + bias.
__global__ __launch_bounds__(256) void gather_kernel(const unsigned int* __restrict__ packs,
                                                     const int* __restrict__ binStart,
                                                     const float* __restrict__ dis,
                                                     const uint2* __restrict__ h4,
                                                     const float* __restrict__ bias,
                                                     float* __restrict__ out) {
    __shared__ unsigned int sorted[CAP];
    __shared__ int cnt[NPB_G], sx[NPB_G], curs[NPB_G];
    __shared__ float disL[NPB_G];
    const int b = blockIdx.x, t = threadIdx.x;
    const int B = b >> 2, sub = b & 3;
    const int beg = binStart[B], end = binStart[B + 1];
    const int n0 = b << 6;

    if (t < NPB_G) {
        cnt[t] = 0;
        disL[t] = (n0 + t < N_NODES) ? dis[n0 + t] : 0.0f;
    }
    __syncthreads();
    for (int i = beg + t; i < end; i += 256) {          // pass 1: count
        unsigned int pk = packs[i];
        if (((pk >> 6) & 3) == (unsigned)sub)
            atomicAdd(&cnt[pk & 63], 1);
    }
    __syncthreads();
    if (t < NPB_G) {                       // wave-0 shuffle scan over 64 bins
        int v = cnt[t];
        int s = v;
#pragma unroll
        for (int off = 1; off < NPB_G; off <<= 1) {
            int u = __shfl_up(s, off);
            if (t >= off) s += u;
        }
        sx[t] = s;                          // inclusive
        curs[t] = s - v;                    // exclusive
    }
    __syncthreads();
    const bool fits = (sx[NPB_G - 1] <= CAP);
    if (fits) {
        for (int i = beg + t; i < end; i += 256) {      // pass 2: place (L2-hot)
            unsigned int pk = packs[i];
            if (((pk >> 6) & 3) == (unsigned)sub) {
                int q = atomicAdd(&curs[pk & 63], 1);
                sorted[q] = ((pk >> 8) << 6) | (pk & 63);
            }
        }
        __syncthreads();
    }

    const int lane = t & 63;
    const int q    = lane >> 4;            // quarter 0..3
    const int ql   = lane & 15;            // feature group (4 features)
    const int w    = t >> 6;

    for (int c = w; c < NPB_G; c += 4) {
        int node = n0 + c;
        if (node >= N_NODES) break;        // uniform per wave
        float a0 = 0.f, a1 = 0.f, a2 = 0.f, a3 = 0.f;
        if (fits) {
            int s1 = sx[c], s0 = s1 - cnt[c];
            int i = s0 + q;
            for (; i + 4 < s1; i += 8) {   // 2 independent loads in flight
                unsigned int pk0 = sorted[i];
                unsigned int pk1 = sorted[i + 4];
                uint2 u0 = h4[(pk0 >> 6) * 16 + ql];
                uint2 u1 = h4[(pk1 >> 6) * 16 + ql];
                a0 += blo(u0.x); a1 += bhi(u0.x); a2 += blo(u0.y); a3 += bhi(u0.y);
                a0 += blo(u1.x); a1 += bhi(u1.x); a2 += blo(u1.y); a3 += bhi(u1.y);
            }
            if (i < s1) {
                unsigned int pk = sorted[i];
                uint2 u = h4[(pk >> 6) * 16 + ql];
                a0 += blo(u.x); a1 += bhi(u.x); a2 += blo(u.y); a3 += bhi(u.y);
            }
        } else {                            // overflow fallback (prob ~0)
            unsigned int want = ((unsigned)sub << 6) | (unsigned)c;
            for (int i = beg + q; i < end; i += 4) {
                unsigned int pk = packs[i];
                if ((pk & 255u) == want) {
                    uint2 u = h4[(pk >> 8) * 16 + ql];
                    a0 += blo(u.x); a1 += bhi(u.x); a2 += blo(u.y); a3 += bhi(u.y);
                }
            }
        }
        a0 += __shfl_xor(a0, 16); a0 += __shfl_xor(a0, 32);
        a1 += __shfl_xor(a1, 16); a1 += __shfl_xor(a1, 32);
        a2 += __shfl_xor(a2, 16); a2 += __shfl_xor(a2, 32);
        a3 += __shfl_xor(a3, 16); a3 += __shfl_xor(a3, 32);

        if (q == 0) {
            float dc = disL[c];
            uint2 us = h4[node * 16 + ql];           // hb[node] = dis*h
            float4 bv = ((const float4*)bias)[ql];
            float4 o;
            o.x = dc * (a0 + blo(us.x)) + bv.x;
            o.y = dc * (a1 + bhi(us.x)) + bv.y;
            o.z = dc * (a2 + blo(us.y)) + bv.z;
            o.w = dc * (a3 + bhi(us.y)) + bv.w;
            ((float4*)out)[node * 16 + ql] = o;
        }
    }
}

// ---------------------------------------------------------------------------
extern "C" void kernel_launch(void* const* d_in, const int* in_sizes, int n_in,
                              void* d_out, int out_size, void* d_ws, size_t ws_size,
                              hipStream_t stream) {
    const float* x   = (const float*)d_in[0];
    const int*   idx = (const int*)d_in[1];   // [2, E], delivered as int32
    const float* W   = (const float*)d_in[2];
    const float* b   = (const float*)d_in[3];
    float*       out = (float*)d_out;

    int* p = (int*)d_ws;
    unsigned int* packs = (unsigned int*)p;  p += N_EDGES;        // 6.4 MB
    int* hist_g   = p;                       p += NB_S * B_SORT;  // 400 KB
    int* binTotal = p;                       p += NB_S + 4;
    int* binStart = p;                       p += NB_S + 4;
    float* dis    = (float*)p;               p += N_NODES;
    p = (int*)(((uintptr_t)p + 15) & ~(uintptr_t)15);             // 16B align
    unsigned short* hb = (unsigned short*)p;                      // 12.8 MB

    hist_kernel<<<B_SORT, 256, 0, stream>>>(idx + N_EDGES, hist_g);
    scanbins_kernel<<<NB_S, B_SORT, 0, stream>>>(hist_g, binTotal);
    scanoff_kernel<<<1, 512, 0, stream>>>(binTotal, binStart);
    scatter_kernel<<<B_SORT, 256, 0, stream>>>(idx, hist_g, binStart, packs);
    degdis_kernel<<<NB_S, 256, 0, stream>>>(packs, binStart, dis);
    gemm_kernel<<<(N_NODES + GEMM_ROWS - 1) / GEMM_ROWS, 256, 0, stream>>>(x, W, dis, hb);
    gather_kernel<<<NB_G, 256, 0, stream>>>(packs, binStart, dis,
                                            (const uint2*)hb, b, out);
}